// Round 5
// baseline (265.175 us; speedup 1.0000x reference)
//
#include <hip/hip_runtime.h>

// RWKV6 TimeMix on MI355X — R10: scan_intra occupancy + bank-conflict fix.
// R9 counters: scan 68us, VALUBusy 50%, Occupancy 34.6%, 2.36M LDS conflicts.
// Causes: (1) 1024 blocks = 4/CU = 16 waves/CU cap; (2) staging writes one
// float component of a float4 -> 16B stride -> 8-way bank conflict; (3) role
// imbalance (ig1 2x expf, ig0 none) -> barrier waits.
// Fixes: C=32/NC=32 (2048 blocks = 8/CU = 32 waves/CU max occupancy, half the
// serial chain); full-float4-per-lane staging via one ds_write_b128
// (conflict-free, balanced: waves 0-1 combo, waves 2-3 v). Compute loop
// unchanged. inter_ln -> grid(32,64)x128thr; state_prop -> 32 chunks.
//
//   K0 prep_w     : 5 weight matrices fp32 -> bf16
//   K1 prep_mix   : token-shift mix -> xr,xk,xv,xw (bf16)
//   K2 gemm_proj  : 4 projections (z-grid), 256^2/8-wave MFMA; r=sigmoid bf16,
//                   k,v bf16, w raw-z fp32 (sigmoid folded into scan)
//   K3 scan_intra : chunked (C=32) scan -> o_intra, rd, U_c, D_c
//   K4 state_prop : S_{c+1} = D_c*S_c + U_c  (32 chunks)
//   K5 inter_ln   : O = o_intra + RD@S_c (MFMA), group-LN, *r -> oh (bf16)
//   K6 gemm_out   : 128^2 MFMA GEMM (proven core) -> d_out (fp32)
//
// Shapes: B=4, T=1024, D=1024, H=16, DH=64. Chunks: NC=32, C=32.

typedef unsigned short u16;
typedef unsigned int   u32;

typedef __attribute__((ext_vector_type(8))) __bf16 bf16x8;
typedef __attribute__((ext_vector_type(4))) float   f32x4;

#define MB (1u << 20)

#define LDS_PTR(p) ((__attribute__((address_space(3))) void*)(p))
#define GLB_PTR(p) ((const __attribute__((address_space(1))) void*)(p))

__device__ __forceinline__ u16 f2bf(float f) {
  u32 u = __builtin_bit_cast(u32, f);
  u += 0x7FFFu + ((u >> 16) & 1u);   // RNE; inputs are finite
  return (u16)(u >> 16);
}
__device__ __forceinline__ float bf2f(u16 x) {
  u32 u = ((u32)x) << 16;
  return __builtin_bit_cast(float, u);
}
__device__ __forceinline__ u32 pack2(float a, float b) {
  return (u32)f2bf(a) | ((u32)f2bf(b) << 16);
}

// ---------------- K0: weights fp32 -> bf16 (5 x 1M elements, 2-wide) --------
__global__ __launch_bounds__(256) void prep_w(
    const float* __restrict__ w0, const float* __restrict__ w1,
    const float* __restrict__ w2, const float* __restrict__ w3,
    const float* __restrict__ w4, u32* __restrict__ out) {
  int idx = blockIdx.x * 256 + threadIdx.x;   // pair index, 5*524288 total
  int m = idx >> 19;                          // matrix id (uniform per block)
  int l = idx & 524287;
  const float* src = (m == 0) ? w0 : (m == 1) ? w1 : (m == 2) ? w2 : (m == 3) ? w3 : w4;
  float2 v = *(const float2*)(src + (size_t)l * 2);
  out[idx] = pack2(v.x, v.y);
}

// ---------------- K1: token-shift mix -> bf16 (2-wide) ----------------------
__global__ __launch_bounds__(256) void prep_mix(
    const float* __restrict__ x,
    const float* __restrict__ tmr, const float* __restrict__ tmk,
    const float* __restrict__ tmv, const float* __restrict__ tmw,
    u32* __restrict__ xr, u32* __restrict__ xk,
    u32* __restrict__ xv, u32* __restrict__ xw) {
  int idx = blockIdx.x * 256 + threadIdx.x;   // pair index over 4*1024*512
  int t  = (idx >> 9) & 1023;
  int d0 = (idx & 511) * 2;
  size_t e = (size_t)idx * 2;
  float2 xc = *(const float2*)(x + e);
  float2 xp = make_float2(0.f, 0.f);
  if (t > 0) xp = *(const float2*)(x + e - 1024);
  float2 tm;
  tm = *(const float2*)(tmr + d0);
  xr[idx] = pack2(tm.x * xc.x + (1.f - tm.x) * xp.x, tm.y * xc.y + (1.f - tm.y) * xp.y);
  tm = *(const float2*)(tmk + d0);
  xk[idx] = pack2(tm.x * xc.x + (1.f - tm.x) * xp.x, tm.y * xc.y + (1.f - tm.y) * xp.y);
  tm = *(const float2*)(tmv + d0);
  xv[idx] = pack2(tm.x * xc.x + (1.f - tm.x) * xp.x, tm.y * xc.y + (1.f - tm.y) * xp.y);
  tm = *(const float2*)(tmw + d0);
  xw[idx] = pack2(tm.x * xc.x + (1.f - tm.x) * xp.x, tm.y * xc.y + (1.f - tm.y) * xp.y);
}

// ---------------- K2: 256x256xBK32 8-wave projection GEMM -------------------
// C[m][n] = sum_k A[m][k]*W[n][k], M=4096, N=1024, K=1024, 4 mats via grid.z.
// 512 threads = 8 waves (2M x 4N); per-wave output 128x64 (M_rep=8, N_rep=4).
// Double-buffered global_load_lds (raw s_barrier + manual vmcnt, never 0 in
// steady state). XOR-swizzled LDS.
// Epilogue (cheap, spill-free): mat 0: sigmoid->bf16; 1,2: bf16; 3: raw fp32.
__global__ __launch_bounds__(512, 1) void gemm_proj(
    const u16* __restrict__ xr, const u16* __restrict__ xk,
    const u16* __restrict__ xv, const u16* __restrict__ xw,
    const u16* __restrict__ Wr, const u16* __restrict__ Wk,
    const u16* __restrict__ Wv, const u16* __restrict__ Ww,
    u16* __restrict__ rO, u16* __restrict__ kO,
    u16* __restrict__ vO, float* __restrict__ wO) {
  constexpr int KITER = 32;
  constexpr int LDK   = 1024;
  __shared__ __align__(16) u16 Asm[2 * 8192];   // 32KB
  __shared__ __align__(16) u16 Bsm[2 * 8192];   // 32KB

  int mat = blockIdx.z;              // uniform
  const u16* A = (mat == 0) ? xr : (mat == 1) ? xk : (mat == 2) ? xv : xw;
  const u16* W = (mat == 0) ? Wr : (mat == 1) ? Wk : (mat == 2) ? Wv : Ww;

  int tid = threadIdx.x;
  int m0 = blockIdx.x * 256, n0 = blockIdx.y * 256;
  int wave = tid >> 6, lane = tid & 63;
  int wm = (wave >> 2) * 128;        // {0,128}
  int wn = (wave & 3) * 64;          // {0,64,128,192}
  int r16 = lane & 15, quad = lane >> 4;

  f32x4 acc[8][4] = {};

  // staging: wave covers rows [wave*32, wave*32+32) of the 256-row tile
  int srow0 = wave * 32 + (lane >> 2);
  int srow1 = srow0 + 16;
  int c4    = lane & 3;
  int q0 = c4 ^ ((srow0 >> 1) & 3);
  int q1 = c4 ^ ((srow1 >> 1) & 3);
  const u16* Ag0 = A + (size_t)(m0 + srow0) * LDK + q0 * 8;
  const u16* Ag1 = A + (size_t)(m0 + srow1) * LDK + q1 * 8;
  const u16* Bg0 = W + (size_t)(n0 + srow0) * LDK + q0 * 8;
  const u16* Bg1 = W + (size_t)(n0 + srow1) * LDK + q1 * 8;
  int ldsOff0 = wave * 1024;         // u16 offset (row wave*32, 32 u16/row)
  int ldsOff1 = wave * 1024 + 512;

  int aoff[8], boff[4];
#pragma unroll
  for (int mt = 0; mt < 8; ++mt) {
    int r = wm + mt * 16 + r16;
    aoff[mt] = r * 32 + (quad ^ ((r >> 1) & 3)) * 8;
  }
#pragma unroll
  for (int nt = 0; nt < 4; ++nt) {
    int r = wn + nt * 16 + r16;
    boff[nt] = r * 32 + (quad ^ ((r >> 1) & 3)) * 8;
  }

#define ISSUE_TILE(t, buf)                                                              \
  do {                                                                                  \
    int _o = (buf) * 8192, _k = (t) * 32;                                               \
    __builtin_amdgcn_global_load_lds(GLB_PTR(Ag0 + _k), LDS_PTR(Asm + _o + ldsOff0), 16, 0, 0); \
    __builtin_amdgcn_global_load_lds(GLB_PTR(Ag1 + _k), LDS_PTR(Asm + _o + ldsOff1), 16, 0, 0); \
    __builtin_amdgcn_global_load_lds(GLB_PTR(Bg0 + _k), LDS_PTR(Bsm + _o + ldsOff0), 16, 0, 0); \
    __builtin_amdgcn_global_load_lds(GLB_PTR(Bg1 + _k), LDS_PTR(Bsm + _o + ldsOff1), 16, 0, 0); \
  } while (0)

  ISSUE_TILE(0, 0);
  ISSUE_TILE(1, 1);                  // 8 loads outstanding

  int cur = 0;
  for (int i = 0; i < KITER; ++i) {
    if (i < KITER - 1) asm volatile("s_waitcnt vmcnt(4)" ::: "memory");
    else               asm volatile("s_waitcnt vmcnt(0)" ::: "memory");
    __builtin_amdgcn_s_barrier();    // all waves' tile-i data landed

    const u16* As = Asm + cur * 8192;
    const u16* Bs = Bsm + cur * 8192;
    bf16x8 af[8], bfm[4];
#pragma unroll
    for (int mt = 0; mt < 8; ++mt) af[mt] = *(const bf16x8*)&As[aoff[mt]];
#pragma unroll
    for (int nt = 0; nt < 4; ++nt) bfm[nt] = *(const bf16x8*)&Bs[boff[nt]];
#pragma unroll
    for (int mt = 0; mt < 8; ++mt)
#pragma unroll
      for (int nt = 0; nt < 4; ++nt)
        acc[mt][nt] = __builtin_amdgcn_mfma_f32_16x16x32_bf16(af[mt], bfm[nt], acc[mt][nt], 0, 0, 0);

    asm volatile("s_waitcnt lgkmcnt(0)" ::: "memory");  // my ds_reads done
    __builtin_amdgcn_s_barrier();                       // everyone's reads done
    if (i + 2 < KITER) ISSUE_TILE(i + 2, cur);          // re-target freed buffer
    cur ^= 1;
  }
#undef ISSUE_TILE

  // epilogue: C/D layout col=lane&15, row=quad*4+reg  [verified m89/m91]
#pragma unroll
  for (int mt = 0; mt < 8; ++mt) {
#pragma unroll
    for (int nt = 0; nt < 4; ++nt) {
#pragma unroll
      for (int rg = 0; rg < 4; ++rg) {
        int row = m0 + wm + mt * 16 + quad * 4 + rg;
        int col = n0 + wn + nt * 16 + r16;
        float v = acc[mt][nt][rg];
        size_t idx = (size_t)row * 1024 + col;
        if (mat == 0)      rO[idx] = f2bf(1.f / (1.f + __expf(-v)));
        else if (mat == 1) kO[idx] = f2bf(v);
        else if (mat == 2) vO[idx] = f2bf(v);
        else               wO[idx] = v;   // raw z; sigmoid folded into scan
      }
    }
  }
}

// ---------------- 128x128 GEMM core (proven clean: R5) ----------------------
template <int KITER>
__device__ __forceinline__ void gemm_core(
    const u16* __restrict__ A, const u16* __restrict__ W, float* __restrict__ O,
    u16* Asm, u16* Bsm) {   // each 3*4096 u16 (3 x 8KB)
  constexpr int LDK = KITER * 32;
  int tid = threadIdx.x;
  int m0 = blockIdx.x * 128, n0 = blockIdx.y * 128;
  int wave = tid >> 6, lane = tid & 63;
  int wm = (wave >> 1) * 64, wn = (wave & 1) * 64;
  int r16 = lane & 15, quad = lane >> 4;

  f32x4 acc[4][4] = {};

  int srow0 = wave * 32 + (lane >> 2);
  int srow1 = srow0 + 16;
  int c4    = lane & 3;
  int q0 = c4 ^ ((srow0 >> 1) & 3);
  int q1 = c4 ^ ((srow1 >> 1) & 3);
  const u16* Ag0 = A + (size_t)(m0 + srow0) * LDK + q0 * 8;
  const u16* Ag1 = A + (size_t)(m0 + srow1) * LDK + q1 * 8;
  const u16* Bg0 = W + (size_t)(n0 + srow0) * LDK + q0 * 8;
  const u16* Bg1 = W + (size_t)(n0 + srow1) * LDK + q1 * 8;
  int ldsOff0 = wave * 1024;
  int ldsOff1 = wave * 1024 + 512;

  int aoff[4], boff[4];
#pragma unroll
  for (int mt = 0; mt < 4; ++mt) {
    int r = wm + mt * 16 + r16;
    aoff[mt] = r * 32 + (quad ^ ((r >> 1) & 3)) * 8;
  }
#pragma unroll
  for (int nt = 0; nt < 4; ++nt) {
    int r = wn + nt * 16 + r16;
    boff[nt] = r * 32 + (quad ^ ((r >> 1) & 3)) * 8;
  }

#define ISSUE_TILE(t, buf)                                                              \
  do {                                                                                  \
    int _o = (buf) * 4096, _k = (t) * 32;                                               \
    __builtin_amdgcn_global_load_lds(GLB_PTR(Ag0 + _k), LDS_PTR(Asm + _o + ldsOff0), 16, 0, 0); \
    __builtin_amdgcn_global_load_lds(GLB_PTR(Ag1 + _k), LDS_PTR(Asm + _o + ldsOff1), 16, 0, 0); \
    __builtin_amdgcn_global_load_lds(GLB_PTR(Bg0 + _k), LDS_PTR(Bsm + _o + ldsOff0), 16, 0, 0); \
    __builtin_amdgcn_global_load_lds(GLB_PTR(Bg1 + _k), LDS_PTR(Bsm + _o + ldsOff1), 16, 0, 0); \
  } while (0)

  ISSUE_TILE(0, 0);
  ISSUE_TILE(1, 1);
  ISSUE_TILE(2, 2);

  int cur = 0;
  for (int i = 0; i < KITER; ++i) {
    if (i < KITER - 2)       asm volatile("s_waitcnt vmcnt(8)" ::: "memory");
    else if (i == KITER - 2) asm volatile("s_waitcnt vmcnt(4)" ::: "memory");
    else                     asm volatile("s_waitcnt vmcnt(0)" ::: "memory");
    __builtin_amdgcn_s_barrier();

    const u16* As = Asm + cur * 4096;
    const u16* Bs = Bsm + cur * 4096;
    bf16x8 af[4], bfm[4];
#pragma unroll
    for (int mt = 0; mt < 4; ++mt) af[mt] = *(const bf16x8*)&As[aoff[mt]];
#pragma unroll
    for (int nt = 0; nt < 4; ++nt) bfm[nt] = *(const bf16x8*)&Bs[boff[nt]];
#pragma unroll
    for (int mt = 0; mt < 4; ++mt)
#pragma unroll
      for (int nt = 0; nt < 4; ++nt)
        acc[mt][nt] = __builtin_amdgcn_mfma_f32_16x16x32_bf16(af[mt], bfm[nt], acc[mt][nt], 0, 0, 0);

    asm volatile("s_waitcnt lgkmcnt(0)" ::: "memory");
    __builtin_amdgcn_s_barrier();
    if (i + 3 < KITER) ISSUE_TILE(i + 3, cur);
    cur = (cur == 2) ? 0 : cur + 1;
  }
#undef ISSUE_TILE

#pragma unroll
  for (int mt = 0; mt < 4; ++mt)
#pragma unroll
    for (int nt = 0; nt < 4; ++nt)
#pragma unroll
      for (int rg = 0; rg < 4; ++rg) {
        int row = m0 + wm + mt * 16 + quad * 4 + rg;
        int col = n0 + wn + nt * 16 + r16;
        O[(size_t)row * 1024 + col] = acc[mt][nt][rg];
      }
}

// K6: output GEMM (M=4096, N=1024, K=1024)
__global__ __launch_bounds__(256) void gemm_out(
    const u16* __restrict__ A, const u16* __restrict__ W, float* __restrict__ O) {
  __shared__ __align__(16) u16 Asm[3 * 4096];
  __shared__ __align__(16) u16 Bsm[3 * 4096];
  gemm_core<32>(A, W, O, Asm, Bsm);
}

// ---------------- K3: intra-chunk scan, C=32, balanced staging --------------
// Block = (chunk c in [0,32), bh), 256 threads = 4 i-groups x 64 j.
// Staging (per 2-step interval): waves 0-1 each build ONE step's full
// float4(r,k,euk,ew) per lane (i=lane) and ds_write_b128 it (conflict-free);
// waves 2-3 load v. ew = sigmoid(z)*exp(-1e-4) [z = raw w-GEMM output].
// 4-slot ring (slot=t&3); one barrier per 2 steps; o-stores deferred one
// interval via part[] (unchanged compute loop).
__global__ __launch_bounds__(256) void scan_intra(
    const u16* __restrict__ rb, const u16* __restrict__ kb,
    const u16* __restrict__ vb, const float* __restrict__ wb,
    const float* __restrict__ u,
    float* __restrict__ o, u16* __restrict__ rd,
    float* __restrict__ U, float* __restrict__ Dc) {
  int c = blockIdx.x, bh = blockIdx.y;
  int b = bh >> 4, h = bh & 15;
  int tid = threadIdx.x, ig = tid >> 6, j = tid & 63;

  __shared__ __align__(16) float4 combo[4][64];  // per-i: (r, k, exp(u+k), ew)
  __shared__ float vs_[4][64];
  __shared__ float part[4][4][64];

  const float EW_SCALE = 0.99990001f;  // exp(-1e-4)

  float s[16];
#pragma unroll
  for (int ii = 0; ii < 16; ++ii) s[ii] = 0.f;

  size_t base = ((size_t)(b * 1024 + c * 32)) * 1024 + h * 64 + j;
  float dloc = 1.0f;
  float uval = (ig < 2) ? u[h * 64 + j] : 0.f;   // combo-stagers: i == lane

  // stage one entry for step t2 into slot sl (role by wave)
#define STAGE(t2, sl)                                                     \
  do {                                                                    \
    size_t _idx = base + (size_t)(t2) * 1024;                             \
    if (ig < 2) {                                                         \
      float _r = bf2f(rb[_idx]);                                          \
      float _k = bf2f(kb[_idx]);                                          \
      float _z = wb[_idx];                                                \
      combo[sl][j] = make_float4(_r, _k, __expf(uval + _k),               \
                                 EW_SCALE / (1.f + __expf(-_z)));         \
    } else {                                                              \
      vs_[sl][j] = bf2f(vb[_idx]);                                        \
    }                                                                     \
  } while (0)

  // prologue: stage steps 0,1 (wave parity picks the step)
  { int p = ig & 1; STAGE(p, p); }
  __syncthreads();

  for (int tt = 0; tt < 32; tt += 2) {
    if (tt + 2 < 32) {
      int p = ig & 1;
      int t2 = tt + 2 + p;
      STAGE(t2, t2 & 3);
    }
    // compute steps tt, tt+1 (slots staged last interval, barrier crossed)
#pragma unroll
    for (int p = 0; p < 2; ++p) {
      int t = tt + p, sl = t & 3;
      float vj = vs_[sl][j];
      float acc = 0.f;
#pragma unroll
      for (int ii = 0; ii < 16; ++ii) {
        float4 cb = combo[sl][ig * 16 + ii];  // broadcast b128
        float tmp = fmaf(cb.z, vj, s[ii]);    // s + exp(u+k)*v
        acc = fmaf(cb.x, tmp, acc);           // += r * (...)
        s[ii] = fmaf(cb.w, s[ii], cb.y * vj); // s = ew*s + k*v
      }
      part[sl][ig][j] = acc;
      if (ig == 0) {
        float4 me = combo[sl][j];
        rd[base + (size_t)t * 1024] = f2bf(me.x * dloc);
        dloc *= me.w;
      }
    }
    // store o for steps tt-2, tt-1 (parts complete since last barrier)
    if (tt >= 2) {
      if (ig == 2) {
        int t = tt - 2, sl = t & 3;
        o[base + (size_t)t * 1024] =
            part[sl][0][j] + part[sl][1][j] + part[sl][2][j] + part[sl][3][j];
      } else if (ig == 3) {
        int t = tt - 1, sl = t & 3;
        o[base + (size_t)t * 1024] =
            part[sl][0][j] + part[sl][1][j] + part[sl][2][j] + part[sl][3][j];
      }
    }
    __syncthreads();
  }
#undef STAGE
  // final two steps' o (slots 30&3=2, 31&3=3)
  if (ig == 2) {
    o[base + (size_t)30 * 1024] = part[2][0][j] + part[2][1][j] + part[2][2][j] + part[2][3][j];
  } else if (ig == 3) {
    o[base + (size_t)31 * 1024] = part[3][0][j] + part[3][1][j] + part[3][2][j] + part[3][3][j];
  }

  float* Ug = U + (size_t)(bh * 32 + c) * 4096;
#pragma unroll
  for (int ii = 0; ii < 16; ++ii) Ug[(ig * 16 + ii) * 64 + j] = s[ii];
  if (ig == 0) Dc[(bh * 32 + c) * 64 + j] = dloc;
}

// ---------------- K4: chunk-state propagation (32 chunks) -------------------
__global__ __launch_bounds__(256) void state_prop(
    float* __restrict__ U, const float* __restrict__ Dc) {
  int bh  = blockIdx.x >> 4;
  int e   = (blockIdx.x & 15) * 256 + threadIdx.x;  // 0..4095
  int i   = e >> 6;
  float acc = 0.f;
  for (int c = 0; c < 32; ++c) {
    float* Ug = U + (size_t)(bh * 32 + c) * 4096 + e;
    float d = Dc[(bh * 32 + c) * 64 + i];
    float uv = *Ug;
    *Ug = acc;                      // write S_c (chunk-initial state)
    acc = fmaf(d, acc, uv);         // S_{c+1} = D_c*S_c + U_c
  }
}

// ---------------- K5: O = o_intra + RD@S_c (MFMA) + group-LN + gate --------
// Block (c in [0,32), bh), 128 threads = 2 waves; wave w owns t-rows
// [w*16, w*16+16) of the 32-row chunk. S_c transposed to bf16 LDS.
__global__ __launch_bounds__(128) void inter_ln(
    const float* __restrict__ o, const u16* __restrict__ rd,
    const u16* __restrict__ rb, const float* __restrict__ U,
    const float* __restrict__ lnw, const float* __restrict__ lnb,
    u16* __restrict__ oh) {
  int c = blockIdx.x, bh = blockIdx.y;
  int b = bh >> 4, h = bh & 15;
  int tid = threadIdx.x, wave = tid >> 6, lane = tid & 63;
  int l15 = lane & 15, quad = lane >> 4;

  __shared__ __align__(16) u16 Sb[64][72];   // Sb[j][i] = S_c[i][j] (bf16)

  const float* Sg = U + (size_t)(bh * 32 + c) * 4096;
#pragma unroll
  for (int q = 0; q < 32; ++q) {
    int e = q * 128 + tid;
    Sb[e & 63][e >> 6] = f2bf(Sg[e]);
  }
  __syncthreads();

  size_t rbase = ((size_t)(b * 1024 + c * 32)) * 1024 + h * 64;

  // A fragments: A[m=l15][k=quad*8+idx] (+32 for kt=1), m-strip = wave*16
  const u16* rdg = rd + rbase + (size_t)(wave * 16 + l15) * 1024 + quad * 8;
  bf16x8 af0 = *(const bf16x8*)(rdg);
  bf16x8 af1 = *(const bf16x8*)(rdg + 32);

  f32x4 acc[4] = {};
#pragma unroll
  for (int nt = 0; nt < 4; ++nt) {
    const u16* bp = &Sb[nt * 16 + l15][quad * 8];
    bf16x8 b0 = *(const bf16x8*)bp;
    bf16x8 b1 = *(const bf16x8*)(bp + 32);
    acc[nt] = __builtin_amdgcn_mfma_f32_16x16x32_bf16(af0, b0, acc[nt], 0, 0, 0);
    acc[nt] = __builtin_amdgcn_mfma_f32_16x16x32_bf16(af1, b1, acc[nt], 0, 0, 0);
  }

  // epilogue: row t = wave*16 + quad*4 + rg; col j = nt*16 + l15.
#pragma unroll
  for (int rg = 0; rg < 4; ++rg) {
    int t = wave * 16 + quad * 4 + rg;
    size_t rowb = rbase + (size_t)t * 1024;
    float v[4];
    float s1 = 0.f, s2 = 0.f;
#pragma unroll
    for (int nt = 0; nt < 4; ++nt) {
      v[nt] = acc[nt][rg] + o[rowb + nt * 16 + l15];
      s1 += v[nt];
      s2 += v[nt] * v[nt];
    }
#pragma unroll
    for (int m = 1; m < 16; m <<= 1) {   // reduce across the quad's 16 lanes
      s1 += __shfl_xor(s1, m, 64);
      s2 += __shfl_xor(s2, m, 64);
    }
    float mu  = s1 * (1.f / 64.f);
    float var = s2 * (1.f / 64.f) - mu * mu;
    float rstd = rsqrtf(var + 1e-5f);
#pragma unroll
    for (int nt = 0; nt < 4; ++nt) {
      int jj = nt * 16 + l15;
      float nv = (v[nt] - mu) * rstd;
      float val = (nv * lnw[jj] + lnb[jj]) * bf2f(rb[rowb + jj]);
      oh[rowb + jj] = f2bf(val);
    }
  }
}

// ---------------- launch -----------------------------------------------------
extern "C" void kernel_launch(void* const* d_in, const int* in_sizes, int n_in,
                              void* d_out, int out_size, void* d_ws, size_t ws_size,
                              hipStream_t stream) {
  const float* x    = (const float*)d_in[0];
  const float* W_r  = (const float*)d_in[1];
  const float* W_k  = (const float*)d_in[2];
  const float* W_v  = (const float*)d_in[3];
  const float* W_w  = (const float*)d_in[4];
  const float* W_o  = (const float*)d_in[5];
  const float* u    = (const float*)d_in[6];
  const float* tm_r = (const float*)d_in[7];
  const float* tm_k = (const float*)d_in[8];
  const float* tm_v = (const float*)d_in[9];
  const float* tm_w = (const float*)d_in[10];
  const float* ln_w = (const float*)d_in[11];
  const float* ln_b = (const float*)d_in[12];
  float* out = (float*)d_out;

  char* ws = (char*)d_ws;
  // region [0,32)MB: xr..xw during prep/gemm_proj; reused as Ubuf afterwards
  u16* xr = (u16*)(ws + (size_t)0 * MB);
  u16* xk = (u16*)(ws + (size_t)8 * MB);
  u16* xv = (u16*)(ws + (size_t)16 * MB);
  u16* xw = (u16*)(ws + (size_t)24 * MB);
  float* Ubuf = (float*)(ws + (size_t)0 * MB);   // 32MB (64bh x 32c x 4096)
  u16* Wb = (u16*)(ws + (size_t)32 * MB);   // 5 x 2MB: Wr,Wk,Wv,Ww,Wo
  u16* Wrb = Wb;
  u16* Wkb = (u16*)(ws + (size_t)34 * MB);
  u16* Wvb = (u16*)(ws + (size_t)36 * MB);
  u16* Wwb = (u16*)(ws + (size_t)38 * MB);
  u16* Wob = (u16*)(ws + (size_t)40 * MB);
  float* Dcbuf = (float*)(ws + (size_t)42 * MB); // 512KB (64bh x 32c x 64)
  u16*   rbuf = (u16*)(ws + (size_t)48 * MB);    // 8MB bf16
  u16*   kbuf = (u16*)(ws + (size_t)56 * MB);    // 8MB bf16
  u16*   vbuf = (u16*)(ws + (size_t)64 * MB);    // 8MB bf16
  float* wbuf = (float*)(ws + (size_t)72 * MB);  // 16MB fp32 (raw z for decay)
  float* obuf = (float*)(ws + (size_t)88 * MB);  // 16MB fp32 o_intra
  u16*  rdbuf = (u16*)(ws + (size_t)104 * MB);   // 8MB bf16
  u16*   ohbuf = (u16*)(ws + (size_t)129 * MB);  // 8MB

  prep_w<<<10240, 256, 0, stream>>>(W_r, W_k, W_v, W_w, W_o, (u32*)Wb);
  prep_mix<<<8192, 256, 0, stream>>>(x, tm_r, tm_k, tm_v, tm_w,
                                     (u32*)xr, (u32*)xk, (u32*)xv, (u32*)xw);
  gemm_proj<<<dim3(16, 4, 4), 512, 0, stream>>>(xr, xk, xv, xw,
                                                Wrb, Wkb, Wvb, Wwb,
                                                rbuf, kbuf, vbuf, wbuf);
  scan_intra<<<dim3(32, 64), 256, 0, stream>>>(rbuf, kbuf, vbuf, wbuf, u,
                                               obuf, rdbuf, Ubuf, Dcbuf);
  state_prop<<<1024, 256, 0, stream>>>(Ubuf, Dcbuf);
  inter_ln<<<dim3(32, 64), 128, 0, stream>>>(obuf, rdbuf, rbuf, Ubuf,
                                             ln_w, ln_b, ohbuf);
  gemm_out<<<dim3(32, 8, 1), 256, 0, stream>>>(ohbuf, Wob, out);
}

// Round 6
// 257.278 us; speedup vs baseline: 1.0307x; 1.0307x over previous
//
#include <hip/hip_runtime.h>

// RWKV6 TimeMix on MI355X — R11: gemm_proj BK=32 -> BK=64.
// R10: gemm_proj 60.4us, MfmaUtil 21.6%, occupancy = 1 block/CU (grid 256,
// 64KB LDS) -> no cross-block TLP; the two barriers per BK=32 step dominate.
// BK=64 halves barrier count (16 iters), doubles MFMA per barrier (64/wave),
// LDS 128KB (still 1 block/CU). LDS linear [256][64] u16; source chunk
// pre-swizzled (l&7)^(l>>3) so LDS[r][c]=global[r][c^(r&7)]; reader chunk
// (kk*4+quad)^(r&7); kk=1 = offset^32. Reads split per-kk to keep live set
// at 48 VGPR (no spill). vmcnt: steady 8, drain 0.
//
//   K0 prep_w     : 5 weight matrices fp32 -> bf16
//   K1 prep_mix   : token-shift mix -> xr,xk,xv,xw (bf16)
//   K2 gemm_proj  : 4 projections (z-grid), 256^2/8-wave/BK64 MFMA
//   K3 scan_intra : chunked (C=32) scan -> o_intra, rd, U_c, D_c
//   K4 state_prop : S_{c+1} = D_c*S_c + U_c  (32 chunks)
//   K5 inter_ln   : O = o_intra + RD@S_c (MFMA), group-LN, *r -> oh (bf16)
//   K6 gemm_out   : 128^2 MFMA GEMM (proven core) -> d_out (fp32)
//
// Shapes: B=4, T=1024, D=1024, H=16, DH=64. Chunks: NC=32, C=32.

typedef unsigned short u16;
typedef unsigned int   u32;

typedef __attribute__((ext_vector_type(8))) __bf16 bf16x8;
typedef __attribute__((ext_vector_type(4))) float   f32x4;

#define MB (1u << 20)

#define LDS_PTR(p) ((__attribute__((address_space(3))) void*)(p))
#define GLB_PTR(p) ((const __attribute__((address_space(1))) void*)(p))

__device__ __forceinline__ u16 f2bf(float f) {
  u32 u = __builtin_bit_cast(u32, f);
  u += 0x7FFFu + ((u >> 16) & 1u);   // RNE; inputs are finite
  return (u16)(u >> 16);
}
__device__ __forceinline__ float bf2f(u16 x) {
  u32 u = ((u32)x) << 16;
  return __builtin_bit_cast(float, u);
}
__device__ __forceinline__ u32 pack2(float a, float b) {
  return (u32)f2bf(a) | ((u32)f2bf(b) << 16);
}

// ---------------- K0: weights fp32 -> bf16 (5 x 1M elements, 2-wide) --------
__global__ __launch_bounds__(256) void prep_w(
    const float* __restrict__ w0, const float* __restrict__ w1,
    const float* __restrict__ w2, const float* __restrict__ w3,
    const float* __restrict__ w4, u32* __restrict__ out) {
  int idx = blockIdx.x * 256 + threadIdx.x;   // pair index, 5*524288 total
  int m = idx >> 19;                          // matrix id (uniform per block)
  int l = idx & 524287;
  const float* src = (m == 0) ? w0 : (m == 1) ? w1 : (m == 2) ? w2 : (m == 3) ? w3 : w4;
  float2 v = *(const float2*)(src + (size_t)l * 2);
  out[idx] = pack2(v.x, v.y);
}

// ---------------- K1: token-shift mix -> bf16 (2-wide) ----------------------
__global__ __launch_bounds__(256) void prep_mix(
    const float* __restrict__ x,
    const float* __restrict__ tmr, const float* __restrict__ tmk,
    const float* __restrict__ tmv, const float* __restrict__ tmw,
    u32* __restrict__ xr, u32* __restrict__ xk,
    u32* __restrict__ xv, u32* __restrict__ xw) {
  int idx = blockIdx.x * 256 + threadIdx.x;   // pair index over 4*1024*512
  int t  = (idx >> 9) & 1023;
  int d0 = (idx & 511) * 2;
  size_t e = (size_t)idx * 2;
  float2 xc = *(const float2*)(x + e);
  float2 xp = make_float2(0.f, 0.f);
  if (t > 0) xp = *(const float2*)(x + e - 1024);
  float2 tm;
  tm = *(const float2*)(tmr + d0);
  xr[idx] = pack2(tm.x * xc.x + (1.f - tm.x) * xp.x, tm.y * xc.y + (1.f - tm.y) * xp.y);
  tm = *(const float2*)(tmk + d0);
  xk[idx] = pack2(tm.x * xc.x + (1.f - tm.x) * xp.x, tm.y * xc.y + (1.f - tm.y) * xp.y);
  tm = *(const float2*)(tmv + d0);
  xv[idx] = pack2(tm.x * xc.x + (1.f - tm.x) * xp.x, tm.y * xc.y + (1.f - tm.y) * xp.y);
  tm = *(const float2*)(tmw + d0);
  xw[idx] = pack2(tm.x * xc.x + (1.f - tm.x) * xp.x, tm.y * xc.y + (1.f - tm.y) * xp.y);
}

// ---------------- K2: 256x256xBK64 8-wave projection GEMM -------------------
// C[m][n] = sum_k A[m][k]*W[n][k], M=4096, N=1024, K=1024, 4 mats via grid.z.
// 512 threads = 8 waves (2M x 4N); per-wave output 128x64 (M_rep=8, N_rep=4).
// Double-buffered global_load_lds, BK=64 (16 K-iters, 64 MFMA/wave/iter).
// LDS linear [256][64] u16 per matrix per buffer (32KB); chunk swizzle via
// pre-swizzled global source; raw s_barrier + counted vmcnt (8 steady, 0 end).
// Epilogue: mat 0: sigmoid->bf16; 1,2: bf16; 3: raw fp32 (sigmoid in scan).
__global__ __launch_bounds__(512, 1) void gemm_proj(
    const u16* __restrict__ xr, const u16* __restrict__ xk,
    const u16* __restrict__ xv, const u16* __restrict__ xw,
    const u16* __restrict__ Wr, const u16* __restrict__ Wk,
    const u16* __restrict__ Wv, const u16* __restrict__ Ww,
    u16* __restrict__ rO, u16* __restrict__ kO,
    u16* __restrict__ vO, float* __restrict__ wO) {
  constexpr int KITER = 16;          // K = 1024 / 64
  constexpr int LDK   = 1024;        // u16 row stride of A and W
  __shared__ __align__(16) u16 Asm[2 * 16384];   // 2 x 32KB ([256][64] u16)
  __shared__ __align__(16) u16 Bsm[2 * 16384];   // 2 x 32KB

  int mat = blockIdx.z;              // uniform
  const u16* A = (mat == 0) ? xr : (mat == 1) ? xk : (mat == 2) ? xv : xw;
  const u16* W = (mat == 0) ? Wr : (mat == 1) ? Wk : (mat == 2) ? Wv : Ww;

  int tid = threadIdx.x;
  int m0 = blockIdx.x * 256, n0 = blockIdx.y * 256;
  int wave = tid >> 6, lane = tid & 63;
  int wm = (wave >> 2) * 128;        // {0,128}
  int wn = (wave & 3) * 64;          // {0,64,128,192}
  int r16 = lane & 15, quad = lane >> 4;

  f32x4 acc[8][4] = {};

  // staging: wave covers rows [wave*32, wave*32+32); issue i covers rows
  // [wave*32+i*8, +8) x 8 chunks. Lane l -> row sub l>>3, chunk l&7; the
  // global source chunk is pre-swizzled (l&7)^(l>>3) so LDS stays linear.
  int lrow  = lane >> 3;             // 0..7
  int lchk  = (lane & 7) ^ lrow;     // swizzled source chunk
  const u16* Ag[4];
  const u16* Bg[4];
#pragma unroll
  for (int i = 0; i < 4; ++i) {
    int row = wave * 32 + i * 8 + lrow;
    Ag[i] = A + (size_t)(m0 + row) * LDK + lchk * 8;
    Bg[i] = W + (size_t)(n0 + row) * LDK + lchk * 8;
  }
  int ldsW = wave * 2048;            // u16 offset of this wave's 32-row stripe

  // read offsets (u16): row r = strip + nt/mt*16 + r16; chunk = quad^(r16&7)
  // for kk=0; kk=1 is offset ^ 32.
  int aoff[8], boff[4];
#pragma unroll
  for (int mt = 0; mt < 8; ++mt) {
    int r = wm + mt * 16 + r16;
    aoff[mt] = r * 64 + (quad ^ (r16 & 7)) * 8;
  }
#pragma unroll
  for (int nt = 0; nt < 4; ++nt) {
    int r = wn + nt * 16 + r16;
    boff[nt] = r * 64 + (quad ^ (r16 & 7)) * 8;
  }

#define ISSUE_TILE(t, buf)                                                              \
  do {                                                                                  \
    int _o = (buf) * 16384 + ldsW, _k = (t) * 64;                                       \
    __builtin_amdgcn_global_load_lds(GLB_PTR(Ag[0] + _k), LDS_PTR(Asm + _o),        16, 0, 0); \
    __builtin_amdgcn_global_load_lds(GLB_PTR(Ag[1] + _k), LDS_PTR(Asm + _o + 512),  16, 0, 0); \
    __builtin_amdgcn_global_load_lds(GLB_PTR(Ag[2] + _k), LDS_PTR(Asm + _o + 1024), 16, 0, 0); \
    __builtin_amdgcn_global_load_lds(GLB_PTR(Ag[3] + _k), LDS_PTR(Asm + _o + 1536), 16, 0, 0); \
    __builtin_amdgcn_global_load_lds(GLB_PTR(Bg[0] + _k), LDS_PTR(Bsm + _o),        16, 0, 0); \
    __builtin_amdgcn_global_load_lds(GLB_PTR(Bg[1] + _k), LDS_PTR(Bsm + _o + 512),  16, 0, 0); \
    __builtin_amdgcn_global_load_lds(GLB_PTR(Bg[2] + _k), LDS_PTR(Bsm + _o + 1024), 16, 0, 0); \
    __builtin_amdgcn_global_load_lds(GLB_PTR(Bg[3] + _k), LDS_PTR(Bsm + _o + 1536), 16, 0, 0); \
  } while (0)

  ISSUE_TILE(0, 0);
  ISSUE_TILE(1, 1);                  // 16 loads outstanding

  int cur = 0;
  for (int i = 0; i < KITER; ++i) {
    if (i < KITER - 1) asm volatile("s_waitcnt vmcnt(8)" ::: "memory");
    else               asm volatile("s_waitcnt vmcnt(0)" ::: "memory");
    __builtin_amdgcn_s_barrier();    // all waves' tile-i data landed

    const u16* As = Asm + cur * 16384;
    const u16* Bs = Bsm + cur * 16384;
#pragma unroll
    for (int kk = 0; kk < 2; ++kk) {
      int kx = kk * 32;              // chunk ^4 == u16 offset ^32
      bf16x8 af[8], bfm[4];
#pragma unroll
      for (int mt = 0; mt < 8; ++mt) af[mt] = *(const bf16x8*)&As[aoff[mt] ^ kx];
#pragma unroll
      for (int nt = 0; nt < 4; ++nt) bfm[nt] = *(const bf16x8*)&Bs[boff[nt] ^ kx];
#pragma unroll
      for (int mt = 0; mt < 8; ++mt)
#pragma unroll
        for (int nt = 0; nt < 4; ++nt)
          acc[mt][nt] = __builtin_amdgcn_mfma_f32_16x16x32_bf16(af[mt], bfm[nt], acc[mt][nt], 0, 0, 0);
    }

    asm volatile("s_waitcnt lgkmcnt(0)" ::: "memory");  // my ds_reads done
    __builtin_amdgcn_s_barrier();                       // everyone's reads done
    if (i + 2 < KITER) ISSUE_TILE(i + 2, cur);          // re-target freed buffer
    cur ^= 1;
  }
#undef ISSUE_TILE

  // epilogue: C/D layout col=lane&15, row=quad*4+reg  [verified m89/m91]
#pragma unroll
  for (int mt = 0; mt < 8; ++mt) {
#pragma unroll
    for (int nt = 0; nt < 4; ++nt) {
#pragma unroll
      for (int rg = 0; rg < 4; ++rg) {
        int row = m0 + wm + mt * 16 + quad * 4 + rg;
        int col = n0 + wn + nt * 16 + r16;
        float v = acc[mt][nt][rg];
        size_t idx = (size_t)row * 1024 + col;
        if (mat == 0)      rO[idx] = f2bf(1.f / (1.f + __expf(-v)));
        else if (mat == 1) kO[idx] = f2bf(v);
        else if (mat == 2) vO[idx] = f2bf(v);
        else               wO[idx] = v;   // raw z; sigmoid folded into scan
      }
    }
  }
}

// ---------------- 128x128 GEMM core (proven clean: R5) ----------------------
template <int KITER>
__device__ __forceinline__ void gemm_core(
    const u16* __restrict__ A, const u16* __restrict__ W, float* __restrict__ O,
    u16* Asm, u16* Bsm) {   // each 3*4096 u16 (3 x 8KB)
  constexpr int LDK = KITER * 32;
  int tid = threadIdx.x;
  int m0 = blockIdx.x * 128, n0 = blockIdx.y * 128;
  int wave = tid >> 6, lane = tid & 63;
  int wm = (wave >> 1) * 64, wn = (wave & 1) * 64;
  int r16 = lane & 15, quad = lane >> 4;

  f32x4 acc[4][4] = {};

  int srow0 = wave * 32 + (lane >> 2);
  int srow1 = srow0 + 16;
  int c4    = lane & 3;
  int q0 = c4 ^ ((srow0 >> 1) & 3);
  int q1 = c4 ^ ((srow1 >> 1) & 3);
  const u16* Ag0 = A + (size_t)(m0 + srow0) * LDK + q0 * 8;
  const u16* Ag1 = A + (size_t)(m0 + srow1) * LDK + q1 * 8;
  const u16* Bg0 = W + (size_t)(n0 + srow0) * LDK + q0 * 8;
  const u16* Bg1 = W + (size_t)(n0 + srow1) * LDK + q1 * 8;
  int ldsOff0 = wave * 1024;
  int ldsOff1 = wave * 1024 + 512;

  int aoff[4], boff[4];
#pragma unroll
  for (int mt = 0; mt < 4; ++mt) {
    int r = wm + mt * 16 + r16;
    aoff[mt] = r * 32 + (quad ^ ((r >> 1) & 3)) * 8;
  }
#pragma unroll
  for (int nt = 0; nt < 4; ++nt) {
    int r = wn + nt * 16 + r16;
    boff[nt] = r * 32 + (quad ^ ((r >> 1) & 3)) * 8;
  }

#define ISSUE_TILE(t, buf)                                                              \
  do {                                                                                  \
    int _o = (buf) * 4096, _k = (t) * 32;                                               \
    __builtin_amdgcn_global_load_lds(GLB_PTR(Ag0 + _k), LDS_PTR(Asm + _o + ldsOff0), 16, 0, 0); \
    __builtin_amdgcn_global_load_lds(GLB_PTR(Ag1 + _k), LDS_PTR(Asm + _o + ldsOff1), 16, 0, 0); \
    __builtin_amdgcn_global_load_lds(GLB_PTR(Bg0 + _k), LDS_PTR(Bsm + _o + ldsOff0), 16, 0, 0); \
    __builtin_amdgcn_global_load_lds(GLB_PTR(Bg1 + _k), LDS_PTR(Bsm + _o + ldsOff1), 16, 0, 0); \
  } while (0)

  ISSUE_TILE(0, 0);
  ISSUE_TILE(1, 1);
  ISSUE_TILE(2, 2);

  int cur = 0;
  for (int i = 0; i < KITER; ++i) {
    if (i < KITER - 2)       asm volatile("s_waitcnt vmcnt(8)" ::: "memory");
    else if (i == KITER - 2) asm volatile("s_waitcnt vmcnt(4)" ::: "memory");
    else                     asm volatile("s_waitcnt vmcnt(0)" ::: "memory");
    __builtin_amdgcn_s_barrier();

    const u16* As = Asm + cur * 4096;
    const u16* Bs = Bsm + cur * 4096;
    bf16x8 af[4], bfm[4];
#pragma unroll
    for (int mt = 0; mt < 4; ++mt) af[mt] = *(const bf16x8*)&As[aoff[mt]];
#pragma unroll
    for (int nt = 0; nt < 4; ++nt) bfm[nt] = *(const bf16x8*)&Bs[boff[nt]];
#pragma unroll
    for (int mt = 0; mt < 4; ++mt)
#pragma unroll
      for (int nt = 0; nt < 4; ++nt)
        acc[mt][nt] = __builtin_amdgcn_mfma_f32_16x16x32_bf16(af[mt], bfm[nt], acc[mt][nt], 0, 0, 0);

    asm volatile("s_waitcnt lgkmcnt(0)" ::: "memory");
    __builtin_amdgcn_s_barrier();
    if (i + 3 < KITER) ISSUE_TILE(i + 3, cur);
    cur = (cur == 2) ? 0 : cur + 1;
  }
#undef ISSUE_TILE

#pragma unroll
  for (int mt = 0; mt < 4; ++mt)
#pragma unroll
    for (int nt = 0; nt < 4; ++nt)
#pragma unroll
      for (int rg = 0; rg < 4; ++rg) {
        int row = m0 + wm + mt * 16 + quad * 4 + rg;
        int col = n0 + wn + nt * 16 + r16;
        O[(size_t)row * 1024 + col] = acc[mt][nt][rg];
      }
}

// K6: output GEMM (M=4096, N=1024, K=1024)
__global__ __launch_bounds__(256) void gemm_out(
    const u16* __restrict__ A, const u16* __restrict__ W, float* __restrict__ O) {
  __shared__ __align__(16) u16 Asm[3 * 4096];
  __shared__ __align__(16) u16 Bsm[3 * 4096];
  gemm_core<32>(A, W, O, Asm, Bsm);
}

// ---------------- K3: intra-chunk scan, C=32, balanced staging --------------
__global__ __launch_bounds__(256) void scan_intra(
    const u16* __restrict__ rb, const u16* __restrict__ kb,
    const u16* __restrict__ vb, const float* __restrict__ wb,
    const float* __restrict__ u,
    float* __restrict__ o, u16* __restrict__ rd,
    float* __restrict__ U, float* __restrict__ Dc) {
  int c = blockIdx.x, bh = blockIdx.y;
  int b = bh >> 4, h = bh & 15;
  int tid = threadIdx.x, ig = tid >> 6, j = tid & 63;

  __shared__ __align__(16) float4 combo[4][64];  // per-i: (r, k, exp(u+k), ew)
  __shared__ float vs_[4][64];
  __shared__ float part[4][4][64];

  const float EW_SCALE = 0.99990001f;  // exp(-1e-4)

  float s[16];
#pragma unroll
  for (int ii = 0; ii < 16; ++ii) s[ii] = 0.f;

  size_t base = ((size_t)(b * 1024 + c * 32)) * 1024 + h * 64 + j;
  float dloc = 1.0f;
  float uval = (ig < 2) ? u[h * 64 + j] : 0.f;   // combo-stagers: i == lane

#define STAGE(t2, sl)                                                     \
  do {                                                                    \
    size_t _idx = base + (size_t)(t2) * 1024;                             \
    if (ig < 2) {                                                         \
      float _r = bf2f(rb[_idx]);                                          \
      float _k = bf2f(kb[_idx]);                                          \
      float _z = wb[_idx];                                                \
      combo[sl][j] = make_float4(_r, _k, __expf(uval + _k),               \
                                 EW_SCALE / (1.f + __expf(-_z)));         \
    } else {                                                              \
      vs_[sl][j] = bf2f(vb[_idx]);                                        \
    }                                                                     \
  } while (0)

  { int p = ig & 1; STAGE(p, p); }
  __syncthreads();

  for (int tt = 0; tt < 32; tt += 2) {
    if (tt + 2 < 32) {
      int p = ig & 1;
      int t2 = tt + 2 + p;
      STAGE(t2, t2 & 3);
    }
#pragma unroll
    for (int p = 0; p < 2; ++p) {
      int t = tt + p, sl = t & 3;
      float vj = vs_[sl][j];
      float acc = 0.f;
#pragma unroll
      for (int ii = 0; ii < 16; ++ii) {
        float4 cb = combo[sl][ig * 16 + ii];  // broadcast b128
        float tmp = fmaf(cb.z, vj, s[ii]);    // s + exp(u+k)*v
        acc = fmaf(cb.x, tmp, acc);           // += r * (...)
        s[ii] = fmaf(cb.w, s[ii], cb.y * vj); // s = ew*s + k*v
      }
      part[sl][ig][j] = acc;
      if (ig == 0) {
        float4 me = combo[sl][j];
        rd[base + (size_t)t * 1024] = f2bf(me.x * dloc);
        dloc *= me.w;
      }
    }
    if (tt >= 2) {
      if (ig == 2) {
        int t = tt - 2, sl = t & 3;
        o[base + (size_t)t * 1024] =
            part[sl][0][j] + part[sl][1][j] + part[sl][2][j] + part[sl][3][j];
      } else if (ig == 3) {
        int t = tt - 1, sl = t & 3;
        o[base + (size_t)t * 1024] =
            part[sl][0][j] + part[sl][1][j] + part[sl][2][j] + part[sl][3][j];
      }
    }
    __syncthreads();
  }
#undef STAGE
  if (ig == 2) {
    o[base + (size_t)30 * 1024] = part[2][0][j] + part[2][1][j] + part[2][2][j] + part[2][3][j];
  } else if (ig == 3) {
    o[base + (size_t)31 * 1024] = part[3][0][j] + part[3][1][j] + part[3][2][j] + part[3][3][j];
  }

  float* Ug = U + (size_t)(bh * 32 + c) * 4096;
#pragma unroll
  for (int ii = 0; ii < 16; ++ii) Ug[(ig * 16 + ii) * 64 + j] = s[ii];
  if (ig == 0) Dc[(bh * 32 + c) * 64 + j] = dloc;
}

// ---------------- K4: chunk-state propagation (32 chunks) -------------------
__global__ __launch_bounds__(256) void state_prop(
    float* __restrict__ U, const float* __restrict__ Dc) {
  int bh  = blockIdx.x >> 4;
  int e   = (blockIdx.x & 15) * 256 + threadIdx.x;  // 0..4095
  int i   = e >> 6;
  float acc = 0.f;
  for (int c = 0; c < 32; ++c) {
    float* Ug = U + (size_t)(bh * 32 + c) * 4096 + e;
    float d = Dc[(bh * 32 + c) * 64 + i];
    float uv = *Ug;
    *Ug = acc;                      // write S_c (chunk-initial state)
    acc = fmaf(d, acc, uv);         // S_{c+1} = D_c*S_c + U_c
  }
}

// ---------------- K5: O = o_intra + RD@S_c (MFMA) + group-LN + gate --------
__global__ __launch_bounds__(128) void inter_ln(
    const float* __restrict__ o, const u16* __restrict__ rd,
    const u16* __restrict__ rb, const float* __restrict__ U,
    const float* __restrict__ lnw, const float* __restrict__ lnb,
    u16* __restrict__ oh) {
  int c = blockIdx.x, bh = blockIdx.y;
  int b = bh >> 4, h = bh & 15;
  int tid = threadIdx.x, wave = tid >> 6, lane = tid & 63;
  int l15 = lane & 15, quad = lane >> 4;

  __shared__ __align__(16) u16 Sb[64][72];   // Sb[j][i] = S_c[i][j] (bf16)

  const float* Sg = U + (size_t)(bh * 32 + c) * 4096;
#pragma unroll
  for (int q = 0; q < 32; ++q) {
    int e = q * 128 + tid;
    Sb[e & 63][e >> 6] = f2bf(Sg[e]);
  }
  __syncthreads();

  size_t rbase = ((size_t)(b * 1024 + c * 32)) * 1024 + h * 64;

  const u16* rdg = rd + rbase + (size_t)(wave * 16 + l15) * 1024 + quad * 8;
  bf16x8 af0 = *(const bf16x8*)(rdg);
  bf16x8 af1 = *(const bf16x8*)(rdg + 32);

  f32x4 acc[4] = {};
#pragma unroll
  for (int nt = 0; nt < 4; ++nt) {
    const u16* bp = &Sb[nt * 16 + l15][quad * 8];
    bf16x8 b0 = *(const bf16x8*)bp;
    bf16x8 b1 = *(const bf16x8*)(bp + 32);
    acc[nt] = __builtin_amdgcn_mfma_f32_16x16x32_bf16(af0, b0, acc[nt], 0, 0, 0);
    acc[nt] = __builtin_amdgcn_mfma_f32_16x16x32_bf16(af1, b1, acc[nt], 0, 0, 0);
  }

#pragma unroll
  for (int rg = 0; rg < 4; ++rg) {
    int t = wave * 16 + quad * 4 + rg;
    size_t rowb = rbase + (size_t)t * 1024;
    float v[4];
    float s1 = 0.f, s2 = 0.f;
#pragma unroll
    for (int nt = 0; nt < 4; ++nt) {
      v[nt] = acc[nt][rg] + o[rowb + nt * 16 + l15];
      s1 += v[nt];
      s2 += v[nt] * v[nt];
    }
#pragma unroll
    for (int m = 1; m < 16; m <<= 1) {   // reduce across the quad's 16 lanes
      s1 += __shfl_xor(s1, m, 64);
      s2 += __shfl_xor(s2, m, 64);
    }
    float mu  = s1 * (1.f / 64.f);
    float var = s2 * (1.f / 64.f) - mu * mu;
    float rstd = rsqrtf(var + 1e-5f);
#pragma unroll
    for (int nt = 0; nt < 4; ++nt) {
      int jj = nt * 16 + l15;
      float nv = (v[nt] - mu) * rstd;
      float val = (nv * lnw[jj] + lnb[jj]) * bf2f(rb[rowb + jj]);
      oh[rowb + jj] = f2bf(val);
    }
  }
}

// ---------------- launch -----------------------------------------------------
extern "C" void kernel_launch(void* const* d_in, const int* in_sizes, int n_in,
                              void* d_out, int out_size, void* d_ws, size_t ws_size,
                              hipStream_t stream) {
  const float* x    = (const float*)d_in[0];
  const float* W_r  = (const float*)d_in[1];
  const float* W_k  = (const float*)d_in[2];
  const float* W_v  = (const float*)d_in[3];
  const float* W_w  = (const float*)d_in[4];
  const float* W_o  = (const float*)d_in[5];
  const float* u    = (const float*)d_in[6];
  const float* tm_r = (const float*)d_in[7];
  const float* tm_k = (const float*)d_in[8];
  const float* tm_v = (const float*)d_in[9];
  const float* tm_w = (const float*)d_in[10];
  const float* ln_w = (const float*)d_in[11];
  const float* ln_b = (const float*)d_in[12];
  float* out = (float*)d_out;

  char* ws = (char*)d_ws;
  // region [0,32)MB: xr..xw during prep/gemm_proj; reused as Ubuf afterwards
  u16* xr = (u16*)(ws + (size_t)0 * MB);
  u16* xk = (u16*)(ws + (size_t)8 * MB);
  u16* xv = (u16*)(ws + (size_t)16 * MB);
  u16* xw = (u16*)(ws + (size_t)24 * MB);
  float* Ubuf = (float*)(ws + (size_t)0 * MB);   // 32MB (64bh x 32c x 4096)
  u16* Wb = (u16*)(ws + (size_t)32 * MB);   // 5 x 2MB: Wr,Wk,Wv,Ww,Wo
  u16* Wrb = Wb;
  u16* Wkb = (u16*)(ws + (size_t)34 * MB);
  u16* Wvb = (u16*)(ws + (size_t)36 * MB);
  u16* Wwb = (u16*)(ws + (size_t)38 * MB);
  u16* Wob = (u16*)(ws + (size_t)40 * MB);
  float* Dcbuf = (float*)(ws + (size_t)42 * MB); // 512KB (64bh x 32c x 64)
  u16*   rbuf = (u16*)(ws + (size_t)48 * MB);    // 8MB bf16
  u16*   kbuf = (u16*)(ws + (size_t)56 * MB);    // 8MB bf16
  u16*   vbuf = (u16*)(ws + (size_t)64 * MB);    // 8MB bf16
  float* wbuf = (float*)(ws + (size_t)72 * MB);  // 16MB fp32 (raw z for decay)
  float* obuf = (float*)(ws + (size_t)88 * MB);  // 16MB fp32 o_intra
  u16*  rdbuf = (u16*)(ws + (size_t)104 * MB);   // 8MB bf16
  u16*   ohbuf = (u16*)(ws + (size_t)129 * MB);  // 8MB

  prep_w<<<10240, 256, 0, stream>>>(W_r, W_k, W_v, W_w, W_o, (u32*)Wb);
  prep_mix<<<8192, 256, 0, stream>>>(x, tm_r, tm_k, tm_v, tm_w,
                                     (u32*)xr, (u32*)xk, (u32*)xv, (u32*)xw);
  gemm_proj<<<dim3(16, 4, 4), 512, 0, stream>>>(xr, xk, xv, xw,
                                                Wrb, Wkb, Wvb, Wwb,
                                                rbuf, kbuf, vbuf, wbuf);
  scan_intra<<<dim3(32, 64), 256, 0, stream>>>(rbuf, kbuf, vbuf, wbuf, u,
                                               obuf, rdbuf, Ubuf, Dcbuf);
  state_prop<<<1024, 256, 0, stream>>>(Ubuf, Dcbuf);
  inter_ln<<<dim3(32, 64), 128, 0, stream>>>(obuf, rdbuf, rbuf, Ubuf,
                                             ln_w, ln_b, ohbuf);
  gemm_out<<<dim3(32, 8, 1), 256, 0, stream>>>(ohbuf, Wob, out);
}

// Round 7
// 242.848 us; speedup vs baseline: 1.0919x; 1.0594x over previous
//
#include <hip/hip_runtime.h>

// RWKV6 TimeMix on MI355X — R12: scan_intra LDS-broadcast fix.
// R11: scan 60us, VALUBusy 56%, HBM 17% -> LDS-pipe-bound: 64 ds_read_b128
// broadcasts per block-step (4 waves x 16 combo reads) ~= 58us of LDS pipe.
// Fix: remap threads (4 ig x 64 j) -> (16 ig4 x 16 jq), s[4][4] per thread.
// One ds_read_b128 now serves 4 quarter-broadcast groups -> 4 combo reads
// per wave-step instead of 16. part[] becomes [4][16][68] (pad 68: g-stride
// = 4 banks -> free 2-way; rows 16B-aligned for b128 writes); o-stores sum 16
// partials with clean b32 reads. Everything else identical to R11.
//
//   K0 prep_w     : 5 weight matrices fp32 -> bf16
//   K1 prep_mix   : token-shift mix -> xr,xk,xv,xw (bf16)
//   K2 gemm_proj  : 4 projections (z-grid), 256^2/8-wave/BK64 MFMA
//   K3 scan_intra : chunked (C=32) scan -> o_intra, rd, U_c, D_c
//   K4 state_prop : S_{c+1} = D_c*S_c + U_c  (32 chunks)
//   K5 inter_ln   : O = o_intra + RD@S_c (MFMA), group-LN, *r -> oh (bf16)
//   K6 gemm_out   : 128^2 MFMA GEMM (proven core) -> d_out (fp32)
//
// Shapes: B=4, T=1024, D=1024, H=16, DH=64. Chunks: NC=32, C=32.

typedef unsigned short u16;
typedef unsigned int   u32;

typedef __attribute__((ext_vector_type(8))) __bf16 bf16x8;
typedef __attribute__((ext_vector_type(4))) float   f32x4;

#define MB (1u << 20)

#define LDS_PTR(p) ((__attribute__((address_space(3))) void*)(p))
#define GLB_PTR(p) ((const __attribute__((address_space(1))) void*)(p))

__device__ __forceinline__ u16 f2bf(float f) {
  u32 u = __builtin_bit_cast(u32, f);
  u += 0x7FFFu + ((u >> 16) & 1u);   // RNE; inputs are finite
  return (u16)(u >> 16);
}
__device__ __forceinline__ float bf2f(u16 x) {
  u32 u = ((u32)x) << 16;
  return __builtin_bit_cast(float, u);
}
__device__ __forceinline__ u32 pack2(float a, float b) {
  return (u32)f2bf(a) | ((u32)f2bf(b) << 16);
}

// ---------------- K0: weights fp32 -> bf16 (5 x 1M elements, 2-wide) --------
__global__ __launch_bounds__(256) void prep_w(
    const float* __restrict__ w0, const float* __restrict__ w1,
    const float* __restrict__ w2, const float* __restrict__ w3,
    const float* __restrict__ w4, u32* __restrict__ out) {
  int idx = blockIdx.x * 256 + threadIdx.x;   // pair index, 5*524288 total
  int m = idx >> 19;                          // matrix id (uniform per block)
  int l = idx & 524287;
  const float* src = (m == 0) ? w0 : (m == 1) ? w1 : (m == 2) ? w2 : (m == 3) ? w3 : w4;
  float2 v = *(const float2*)(src + (size_t)l * 2);
  out[idx] = pack2(v.x, v.y);
}

// ---------------- K1: token-shift mix -> bf16 (2-wide) ----------------------
__global__ __launch_bounds__(256) void prep_mix(
    const float* __restrict__ x,
    const float* __restrict__ tmr, const float* __restrict__ tmk,
    const float* __restrict__ tmv, const float* __restrict__ tmw,
    u32* __restrict__ xr, u32* __restrict__ xk,
    u32* __restrict__ xv, u32* __restrict__ xw) {
  int idx = blockIdx.x * 256 + threadIdx.x;   // pair index over 4*1024*512
  int t  = (idx >> 9) & 1023;
  int d0 = (idx & 511) * 2;
  size_t e = (size_t)idx * 2;
  float2 xc = *(const float2*)(x + e);
  float2 xp = make_float2(0.f, 0.f);
  if (t > 0) xp = *(const float2*)(x + e - 1024);
  float2 tm;
  tm = *(const float2*)(tmr + d0);
  xr[idx] = pack2(tm.x * xc.x + (1.f - tm.x) * xp.x, tm.y * xc.y + (1.f - tm.y) * xp.y);
  tm = *(const float2*)(tmk + d0);
  xk[idx] = pack2(tm.x * xc.x + (1.f - tm.x) * xp.x, tm.y * xc.y + (1.f - tm.y) * xp.y);
  tm = *(const float2*)(tmv + d0);
  xv[idx] = pack2(tm.x * xc.x + (1.f - tm.x) * xp.x, tm.y * xc.y + (1.f - tm.y) * xp.y);
  tm = *(const float2*)(tmw + d0);
  xw[idx] = pack2(tm.x * xc.x + (1.f - tm.x) * xp.x, tm.y * xc.y + (1.f - tm.y) * xp.y);
}

// ---------------- K2: 256x256xBK64 8-wave projection GEMM -------------------
__global__ __launch_bounds__(512, 1) void gemm_proj(
    const u16* __restrict__ xr, const u16* __restrict__ xk,
    const u16* __restrict__ xv, const u16* __restrict__ xw,
    const u16* __restrict__ Wr, const u16* __restrict__ Wk,
    const u16* __restrict__ Wv, const u16* __restrict__ Ww,
    u16* __restrict__ rO, u16* __restrict__ kO,
    u16* __restrict__ vO, float* __restrict__ wO) {
  constexpr int KITER = 16;          // K = 1024 / 64
  constexpr int LDK   = 1024;        // u16 row stride of A and W
  __shared__ __align__(16) u16 Asm[2 * 16384];   // 2 x 32KB ([256][64] u16)
  __shared__ __align__(16) u16 Bsm[2 * 16384];   // 2 x 32KB

  int mat = blockIdx.z;              // uniform
  const u16* A = (mat == 0) ? xr : (mat == 1) ? xk : (mat == 2) ? xv : xw;
  const u16* W = (mat == 0) ? Wr : (mat == 1) ? Wk : (mat == 2) ? Wv : Ww;

  int tid = threadIdx.x;
  int m0 = blockIdx.x * 256, n0 = blockIdx.y * 256;
  int wave = tid >> 6, lane = tid & 63;
  int wm = (wave >> 2) * 128;        // {0,128}
  int wn = (wave & 3) * 64;          // {0,64,128,192}
  int r16 = lane & 15, quad = lane >> 4;

  f32x4 acc[8][4] = {};

  int lrow  = lane >> 3;             // 0..7
  int lchk  = (lane & 7) ^ lrow;     // swizzled source chunk
  const u16* Ag[4];
  const u16* Bg[4];
#pragma unroll
  for (int i = 0; i < 4; ++i) {
    int row = wave * 32 + i * 8 + lrow;
    Ag[i] = A + (size_t)(m0 + row) * LDK + lchk * 8;
    Bg[i] = W + (size_t)(n0 + row) * LDK + lchk * 8;
  }
  int ldsW = wave * 2048;            // u16 offset of this wave's 32-row stripe

  int aoff[8], boff[4];
#pragma unroll
  for (int mt = 0; mt < 8; ++mt) {
    int r = wm + mt * 16 + r16;
    aoff[mt] = r * 64 + (quad ^ (r16 & 7)) * 8;
  }
#pragma unroll
  for (int nt = 0; nt < 4; ++nt) {
    int r = wn + nt * 16 + r16;
    boff[nt] = r * 64 + (quad ^ (r16 & 7)) * 8;
  }

#define ISSUE_TILE(t, buf)                                                              \
  do {                                                                                  \
    int _o = (buf) * 16384 + ldsW, _k = (t) * 64;                                       \
    __builtin_amdgcn_global_load_lds(GLB_PTR(Ag[0] + _k), LDS_PTR(Asm + _o),        16, 0, 0); \
    __builtin_amdgcn_global_load_lds(GLB_PTR(Ag[1] + _k), LDS_PTR(Asm + _o + 512),  16, 0, 0); \
    __builtin_amdgcn_global_load_lds(GLB_PTR(Ag[2] + _k), LDS_PTR(Asm + _o + 1024), 16, 0, 0); \
    __builtin_amdgcn_global_load_lds(GLB_PTR(Ag[3] + _k), LDS_PTR(Asm + _o + 1536), 16, 0, 0); \
    __builtin_amdgcn_global_load_lds(GLB_PTR(Bg[0] + _k), LDS_PTR(Bsm + _o),        16, 0, 0); \
    __builtin_amdgcn_global_load_lds(GLB_PTR(Bg[1] + _k), LDS_PTR(Bsm + _o + 512),  16, 0, 0); \
    __builtin_amdgcn_global_load_lds(GLB_PTR(Bg[2] + _k), LDS_PTR(Bsm + _o + 1024), 16, 0, 0); \
    __builtin_amdgcn_global_load_lds(GLB_PTR(Bg[3] + _k), LDS_PTR(Bsm + _o + 1536), 16, 0, 0); \
  } while (0)

  ISSUE_TILE(0, 0);
  ISSUE_TILE(1, 1);                  // 16 loads outstanding

  int cur = 0;
  for (int i = 0; i < KITER; ++i) {
    if (i < KITER - 1) asm volatile("s_waitcnt vmcnt(8)" ::: "memory");
    else               asm volatile("s_waitcnt vmcnt(0)" ::: "memory");
    __builtin_amdgcn_s_barrier();    // all waves' tile-i data landed

    const u16* As = Asm + cur * 16384;
    const u16* Bs = Bsm + cur * 16384;
#pragma unroll
    for (int kk = 0; kk < 2; ++kk) {
      int kx = kk * 32;              // chunk ^4 == u16 offset ^32
      bf16x8 af[8], bfm[4];
#pragma unroll
      for (int mt = 0; mt < 8; ++mt) af[mt] = *(const bf16x8*)&As[aoff[mt] ^ kx];
#pragma unroll
      for (int nt = 0; nt < 4; ++nt) bfm[nt] = *(const bf16x8*)&Bs[boff[nt] ^ kx];
#pragma unroll
      for (int mt = 0; mt < 8; ++mt)
#pragma unroll
        for (int nt = 0; nt < 4; ++nt)
          acc[mt][nt] = __builtin_amdgcn_mfma_f32_16x16x32_bf16(af[mt], bfm[nt], acc[mt][nt], 0, 0, 0);
    }

    asm volatile("s_waitcnt lgkmcnt(0)" ::: "memory");  // my ds_reads done
    __builtin_amdgcn_s_barrier();                       // everyone's reads done
    if (i + 2 < KITER) ISSUE_TILE(i + 2, cur);          // re-target freed buffer
    cur ^= 1;
  }
#undef ISSUE_TILE

  // epilogue: C/D layout col=lane&15, row=quad*4+reg  [verified m89/m91]
#pragma unroll
  for (int mt = 0; mt < 8; ++mt) {
#pragma unroll
    for (int nt = 0; nt < 4; ++nt) {
#pragma unroll
      for (int rg = 0; rg < 4; ++rg) {
        int row = m0 + wm + mt * 16 + quad * 4 + rg;
        int col = n0 + wn + nt * 16 + r16;
        float v = acc[mt][nt][rg];
        size_t idx = (size_t)row * 1024 + col;
        if (mat == 0)      rO[idx] = f2bf(1.f / (1.f + __expf(-v)));
        else if (mat == 1) kO[idx] = f2bf(v);
        else if (mat == 2) vO[idx] = f2bf(v);
        else               wO[idx] = v;   // raw z; sigmoid folded into scan
      }
    }
  }
}

// ---------------- 128x128 GEMM core (proven clean: R5) ----------------------
template <int KITER>
__device__ __forceinline__ void gemm_core(
    const u16* __restrict__ A, const u16* __restrict__ W, float* __restrict__ O,
    u16* Asm, u16* Bsm) {   // each 3*4096 u16 (3 x 8KB)
  constexpr int LDK = KITER * 32;
  int tid = threadIdx.x;
  int m0 = blockIdx.x * 128, n0 = blockIdx.y * 128;
  int wave = tid >> 6, lane = tid & 63;
  int wm = (wave >> 1) * 64, wn = (wave & 1) * 64;
  int r16 = lane & 15, quad = lane >> 4;

  f32x4 acc[4][4] = {};

  int srow0 = wave * 32 + (lane >> 2);
  int srow1 = srow0 + 16;
  int c4    = lane & 3;
  int q0 = c4 ^ ((srow0 >> 1) & 3);
  int q1 = c4 ^ ((srow1 >> 1) & 3);
  const u16* Ag0 = A + (size_t)(m0 + srow0) * LDK + q0 * 8;
  const u16* Ag1 = A + (size_t)(m0 + srow1) * LDK + q1 * 8;
  const u16* Bg0 = W + (size_t)(n0 + srow0) * LDK + q0 * 8;
  const u16* Bg1 = W + (size_t)(n0 + srow1) * LDK + q1 * 8;
  int ldsOff0 = wave * 1024;
  int ldsOff1 = wave * 1024 + 512;

  int aoff[4], boff[4];
#pragma unroll
  for (int mt = 0; mt < 4; ++mt) {
    int r = wm + mt * 16 + r16;
    aoff[mt] = r * 32 + (quad ^ ((r >> 1) & 3)) * 8;
  }
#pragma unroll
  for (int nt = 0; nt < 4; ++nt) {
    int r = wn + nt * 16 + r16;
    boff[nt] = r * 32 + (quad ^ ((r >> 1) & 3)) * 8;
  }

#define ISSUE_TILE(t, buf)                                                              \
  do {                                                                                  \
    int _o = (buf) * 4096, _k = (t) * 32;                                               \
    __builtin_amdgcn_global_load_lds(GLB_PTR(Ag0 + _k), LDS_PTR(Asm + _o + ldsOff0), 16, 0, 0); \
    __builtin_amdgcn_global_load_lds(GLB_PTR(Ag1 + _k), LDS_PTR(Asm + _o + ldsOff1), 16, 0, 0); \
    __builtin_amdgcn_global_load_lds(GLB_PTR(Bg0 + _k), LDS_PTR(Bsm + _o + ldsOff0), 16, 0, 0); \
    __builtin_amdgcn_global_load_lds(GLB_PTR(Bg1 + _k), LDS_PTR(Bsm + _o + ldsOff1), 16, 0, 0); \
  } while (0)

  ISSUE_TILE(0, 0);
  ISSUE_TILE(1, 1);
  ISSUE_TILE(2, 2);

  int cur = 0;
  for (int i = 0; i < KITER; ++i) {
    if (i < KITER - 2)       asm volatile("s_waitcnt vmcnt(8)" ::: "memory");
    else if (i == KITER - 2) asm volatile("s_waitcnt vmcnt(4)" ::: "memory");
    else                     asm volatile("s_waitcnt vmcnt(0)" ::: "memory");
    __builtin_amdgcn_s_barrier();

    const u16* As = Asm + cur * 4096;
    const u16* Bs = Bsm + cur * 4096;
    bf16x8 af[4], bfm[4];
#pragma unroll
    for (int mt = 0; mt < 4; ++mt) af[mt] = *(const bf16x8*)&As[aoff[mt]];
#pragma unroll
    for (int nt = 0; nt < 4; ++nt) bfm[nt] = *(const bf16x8*)&Bs[boff[nt]];
#pragma unroll
    for (int mt = 0; mt < 4; ++mt)
#pragma unroll
      for (int nt = 0; nt < 4; ++nt)
        acc[mt][nt] = __builtin_amdgcn_mfma_f32_16x16x32_bf16(af[mt], bfm[nt], acc[mt][nt], 0, 0, 0);

    asm volatile("s_waitcnt lgkmcnt(0)" ::: "memory");
    __builtin_amdgcn_s_barrier();
    if (i + 3 < KITER) ISSUE_TILE(i + 3, cur);
    cur = (cur == 2) ? 0 : cur + 1;
  }
#undef ISSUE_TILE

#pragma unroll
  for (int mt = 0; mt < 4; ++mt)
#pragma unroll
    for (int nt = 0; nt < 4; ++nt)
#pragma unroll
      for (int rg = 0; rg < 4; ++rg) {
        int row = m0 + wm + mt * 16 + quad * 4 + rg;
        int col = n0 + wn + nt * 16 + r16;
        O[(size_t)row * 1024 + col] = acc[mt][nt][rg];
      }
}

// K6: output GEMM (M=4096, N=1024, K=1024)
__global__ __launch_bounds__(256) void gemm_out(
    const u16* __restrict__ A, const u16* __restrict__ W, float* __restrict__ O) {
  __shared__ __align__(16) u16 Asm[3 * 4096];
  __shared__ __align__(16) u16 Bsm[3 * 4096];
  gemm_core<32>(A, W, O, Asm, Bsm);
}

// ---------------- K3: intra-chunk scan, C=32, 16x16 thread map --------------
// Block = (chunk c in [0,32), bh), 256 threads: ig4 = tid>>4 in [0,16) owns
// i in [ig4*4, +4); jq = tid&15 owns j in [jq*4, +4). s[4][4] per thread.
// Per wave-step LDS: 4 combo b128 (4 quarter-broadcast groups each, 2-way) +
// 1 vs b128 + 1 part b128 write. part[4][16][68]: 68-pad -> g-stride 4 banks
// (free 2-way), rows 16B-aligned. Waves 0-1 stage combo (lane = i), waves
// 2-3 stage v; wave 0 also produces rd/dloc from a clean vector b128 read.
__global__ __launch_bounds__(256) void scan_intra(
    const u16* __restrict__ rb, const u16* __restrict__ kb,
    const u16* __restrict__ vb, const float* __restrict__ wb,
    const float* __restrict__ u,
    float* __restrict__ o, u16* __restrict__ rd,
    float* __restrict__ U, float* __restrict__ Dc) {
  int c = blockIdx.x, bh = blockIdx.y;
  int b = bh >> 4, h = bh & 15;
  int tid = threadIdx.x;
  int wave = tid >> 6, lane = tid & 63;
  int ig4 = tid >> 4, jq = tid & 15;

  __shared__ __align__(16) float4 combo[4][64];  // per-i: (r, k, exp(u+k), ew)
  __shared__ __align__(16) float4 vs4[4][16];    // v, viewed 4-wide
  __shared__ __align__(16) float  part[4][16][68];

  const float EW_SCALE = 0.99990001f;  // exp(-1e-4)

  float s[4][4];
#pragma unroll
  for (int ii = 0; ii < 4; ++ii)
#pragma unroll
    for (int jj = 0; jj < 4; ++jj) s[ii][jj] = 0.f;

  size_t base = ((size_t)(b * 1024 + c * 32)) * 1024 + h * 64 + lane;
  float dloc = 1.0f;
  float uval = (wave < 2) ? u[h * 64 + lane] : 0.f;   // combo stagers: i==lane

#define STAGE(t2, sl)                                                     \
  do {                                                                    \
    size_t _idx = base + (size_t)(t2) * 1024;                             \
    if (wave < 2) {                                                       \
      float _r = bf2f(rb[_idx]);                                          \
      float _k = bf2f(kb[_idx]);                                          \
      float _z = wb[_idx];                                                \
      combo[sl][lane] = make_float4(_r, _k, __expf(uval + _k),            \
                                    EW_SCALE / (1.f + __expf(-_z)));      \
    } else {                                                              \
      ((float*)vs4)[(sl) * 64 + lane] = bf2f(vb[_idx]);                   \
    }                                                                     \
  } while (0)

  // prologue: stage steps 0,1 (wave parity picks the step)
  { int p = wave & 1; STAGE(p, p); }
  __syncthreads();

  for (int tt = 0; tt < 32; tt += 2) {
    if (tt + 2 < 32) {
      int p = wave & 1;
      int t2 = tt + 2 + p;
      STAGE(t2, t2 & 3);
    }
    // compute steps tt, tt+1 (slots staged last interval, barrier crossed)
#pragma unroll
    for (int p = 0; p < 2; ++p) {
      int t = tt + p, sl = t & 3;
      float4 vv = vs4[sl][jq];
      float4 cb0 = combo[sl][ig4 * 4 + 0];
      float4 cb1 = combo[sl][ig4 * 4 + 1];
      float4 cb2 = combo[sl][ig4 * 4 + 2];
      float4 cb3 = combo[sl][ig4 * 4 + 3];
      float ac0 = 0.f, ac1 = 0.f, ac2 = 0.f, ac3 = 0.f;
#define ROW(cb, ii)                                                       \
      do {                                                                \
        float t0 = fmaf(cb.z, vv.x, s[ii][0]);                            \
        float t1 = fmaf(cb.z, vv.y, s[ii][1]);                            \
        float t2_ = fmaf(cb.z, vv.z, s[ii][2]);                           \
        float t3 = fmaf(cb.z, vv.w, s[ii][3]);                            \
        ac0 = fmaf(cb.x, t0, ac0);                                        \
        ac1 = fmaf(cb.x, t1, ac1);                                        \
        ac2 = fmaf(cb.x, t2_, ac2);                                       \
        ac3 = fmaf(cb.x, t3, ac3);                                        \
        s[ii][0] = fmaf(cb.w, s[ii][0], cb.y * vv.x);                     \
        s[ii][1] = fmaf(cb.w, s[ii][1], cb.y * vv.y);                     \
        s[ii][2] = fmaf(cb.w, s[ii][2], cb.y * vv.z);                     \
        s[ii][3] = fmaf(cb.w, s[ii][3], cb.y * vv.w);                     \
      } while (0)
      ROW(cb0, 0); ROW(cb1, 1); ROW(cb2, 2); ROW(cb3, 3);
#undef ROW
      *(float4*)&part[sl][ig4][jq * 4] = make_float4(ac0, ac1, ac2, ac3);
      if (wave == 0) {
        float4 me = combo[sl][lane];          // i == lane, vector b128
        rd[base + (size_t)t * 1024] = f2bf(me.x * dloc);
        dloc *= me.w;
      }
    }
    // store o for steps tt-2, tt-1 (parts complete since last barrier)
    if (tt >= 2) {
      if (wave == 2) {
        int t = tt - 2, sl = t & 3;
        float sum = 0.f;
#pragma unroll
        for (int g = 0; g < 16; ++g) sum += part[sl][g][lane];
        o[base + (size_t)t * 1024] = sum;
      } else if (wave == 3) {
        int t = tt - 1, sl = t & 3;
        float sum = 0.f;
#pragma unroll
        for (int g = 0; g < 16; ++g) sum += part[sl][g][lane];
        o[base + (size_t)t * 1024] = sum;
      }
    }
    __syncthreads();
  }
#undef STAGE
  // final two steps' o (slots 30&3=2, 31&3=3)
  if (wave == 2) {
    float sum = 0.f;
#pragma unroll
    for (int g = 0; g < 16; ++g) sum += part[2][g][lane];
    o[base + (size_t)30 * 1024] = sum;
  } else if (wave == 3) {
    float sum = 0.f;
#pragma unroll
    for (int g = 0; g < 16; ++g) sum += part[3][g][lane];
    o[base + (size_t)31 * 1024] = sum;
  }

  float* Ug = U + (size_t)(bh * 32 + c) * 4096;
#pragma unroll
  for (int ii = 0; ii < 4; ++ii) {
    *(float4*)&Ug[(ig4 * 4 + ii) * 64 + jq * 4] =
        make_float4(s[ii][0], s[ii][1], s[ii][2], s[ii][3]);
  }
  if (wave == 0) Dc[(bh * 32 + c) * 64 + lane] = dloc;
}

// ---------------- K4: chunk-state propagation (32 chunks) -------------------
__global__ __launch_bounds__(256) void state_prop(
    float* __restrict__ U, const float* __restrict__ Dc) {
  int bh  = blockIdx.x >> 4;
  int e   = (blockIdx.x & 15) * 256 + threadIdx.x;  // 0..4095
  int i   = e >> 6;
  float acc = 0.f;
  for (int c = 0; c < 32; ++c) {
    float* Ug = U + (size_t)(bh * 32 + c) * 4096 + e;
    float d = Dc[(bh * 32 + c) * 64 + i];
    float uv = *Ug;
    *Ug = acc;                      // write S_c (chunk-initial state)
    acc = fmaf(d, acc, uv);         // S_{c+1} = D_c*S_c + U_c
  }
}

// ---------------- K5: O = o_intra + RD@S_c (MFMA) + group-LN + gate --------
__global__ __launch_bounds__(128) void inter_ln(
    const float* __restrict__ o, const u16* __restrict__ rd,
    const u16* __restrict__ rb, const float* __restrict__ U,
    const float* __restrict__ lnw, const float* __restrict__ lnb,
    u16* __restrict__ oh) {
  int c = blockIdx.x, bh = blockIdx.y;
  int b = bh >> 4, h = bh & 15;
  int tid = threadIdx.x, wave = tid >> 6, lane = tid & 63;
  int l15 = lane & 15, quad = lane >> 4;

  __shared__ __align__(16) u16 Sb[64][72];   // Sb[j][i] = S_c[i][j] (bf16)

  const float* Sg = U + (size_t)(bh * 32 + c) * 4096;
#pragma unroll
  for (int q = 0; q < 32; ++q) {
    int e = q * 128 + tid;
    Sb[e & 63][e >> 6] = f2bf(Sg[e]);
  }
  __syncthreads();

  size_t rbase = ((size_t)(b * 1024 + c * 32)) * 1024 + h * 64;

  const u16* rdg = rd + rbase + (size_t)(wave * 16 + l15) * 1024 + quad * 8;
  bf16x8 af0 = *(const bf16x8*)(rdg);
  bf16x8 af1 = *(const bf16x8*)(rdg + 32);

  f32x4 acc[4] = {};
#pragma unroll
  for (int nt = 0; nt < 4; ++nt) {
    const u16* bp = &Sb[nt * 16 + l15][quad * 8];
    bf16x8 b0 = *(const bf16x8*)bp;
    bf16x8 b1 = *(const bf16x8*)(bp + 32);
    acc[nt] = __builtin_amdgcn_mfma_f32_16x16x32_bf16(af0, b0, acc[nt], 0, 0, 0);
    acc[nt] = __builtin_amdgcn_mfma_f32_16x16x32_bf16(af1, b1, acc[nt], 0, 0, 0);
  }

#pragma unroll
  for (int rg = 0; rg < 4; ++rg) {
    int t = wave * 16 + quad * 4 + rg;
    size_t rowb = rbase + (size_t)t * 1024;
    float v[4];
    float s1 = 0.f, s2 = 0.f;
#pragma unroll
    for (int nt = 0; nt < 4; ++nt) {
      v[nt] = acc[nt][rg] + o[rowb + nt * 16 + l15];
      s1 += v[nt];
      s2 += v[nt] * v[nt];
    }
#pragma unroll
    for (int m = 1; m < 16; m <<= 1) {   // reduce across the quad's 16 lanes
      s1 += __shfl_xor(s1, m, 64);
      s2 += __shfl_xor(s2, m, 64);
    }
    float mu  = s1 * (1.f / 64.f);
    float var = s2 * (1.f / 64.f) - mu * mu;
    float rstd = rsqrtf(var + 1e-5f);
#pragma unroll
    for (int nt = 0; nt < 4; ++nt) {
      int jj = nt * 16 + l15;
      float nv = (v[nt] - mu) * rstd;
      float val = (nv * lnw[jj] + lnb[jj]) * bf2f(rb[rowb + jj]);
      oh[rowb + jj] = f2bf(val);
    }
  }
}

// ---------------- launch -----------------------------------------------------
extern "C" void kernel_launch(void* const* d_in, const int* in_sizes, int n_in,
                              void* d_out, int out_size, void* d_ws, size_t ws_size,
                              hipStream_t stream) {
  const float* x    = (const float*)d_in[0];
  const float* W_r  = (const float*)d_in[1];
  const float* W_k  = (const float*)d_in[2];
  const float* W_v  = (const float*)d_in[3];
  const float* W_w  = (const float*)d_in[4];
  const float* W_o  = (const float*)d_in[5];
  const float* u    = (const float*)d_in[6];
  const float* tm_r = (const float*)d_in[7];
  const float* tm_k = (const float*)d_in[8];
  const float* tm_v = (const float*)d_in[9];
  const float* tm_w = (const float*)d_in[10];
  const float* ln_w = (const float*)d_in[11];
  const float* ln_b = (const float*)d_in[12];
  float* out = (float*)d_out;

  char* ws = (char*)d_ws;
  // region [0,32)MB: xr..xw during prep/gemm_proj; reused as Ubuf afterwards
  u16* xr = (u16*)(ws + (size_t)0 * MB);
  u16* xk = (u16*)(ws + (size_t)8 * MB);
  u16* xv = (u16*)(ws + (size_t)16 * MB);
  u16* xw = (u16*)(ws + (size_t)24 * MB);
  float* Ubuf = (float*)(ws + (size_t)0 * MB);   // 32MB (64bh x 32c x 4096)
  u16* Wb = (u16*)(ws + (size_t)32 * MB);   // 5 x 2MB: Wr,Wk,Wv,Ww,Wo
  u16* Wrb = Wb;
  u16* Wkb = (u16*)(ws + (size_t)34 * MB);
  u16* Wvb = (u16*)(ws + (size_t)36 * MB);
  u16* Wwb = (u16*)(ws + (size_t)38 * MB);
  u16* Wob = (u16*)(ws + (size_t)40 * MB);
  float* Dcbuf = (float*)(ws + (size_t)42 * MB); // 512KB (64bh x 32c x 64)
  u16*   rbuf = (u16*)(ws + (size_t)48 * MB);    // 8MB bf16
  u16*   kbuf = (u16*)(ws + (size_t)56 * MB);    // 8MB bf16
  u16*   vbuf = (u16*)(ws + (size_t)64 * MB);    // 8MB bf16
  float* wbuf = (float*)(ws + (size_t)72 * MB);  // 16MB fp32 (raw z for decay)
  float* obuf = (float*)(ws + (size_t)88 * MB);  // 16MB fp32 o_intra
  u16*  rdbuf = (u16*)(ws + (size_t)104 * MB);   // 8MB bf16
  u16*   ohbuf = (u16*)(ws + (size_t)129 * MB);  // 8MB

  prep_w<<<10240, 256, 0, stream>>>(W_r, W_k, W_v, W_w, W_o, (u32*)Wb);
  prep_mix<<<8192, 256, 0, stream>>>(x, tm_r, tm_k, tm_v, tm_w,
                                     (u32*)xr, (u32*)xk, (u32*)xv, (u32*)xw);
  gemm_proj<<<dim3(16, 4, 4), 512, 0, stream>>>(xr, xk, xv, xw,
                                                Wrb, Wkb, Wvb, Wwb,
                                                rbuf, kbuf, vbuf, wbuf);
  scan_intra<<<dim3(32, 64), 256, 0, stream>>>(rbuf, kbuf, vbuf, wbuf, u,
                                               obuf, rdbuf, Ubuf, Dcbuf);
  state_prop<<<1024, 256, 0, stream>>>(Ubuf, Dcbuf);
  inter_ln<<<dim3(32, 64), 128, 0, stream>>>(obuf, rdbuf, rbuf, Ubuf,
                                             ln_w, ln_b, ohbuf);
  gemm_out<<<dim3(32, 8, 1), 256, 0, stream>>>(ohbuf, Wob, out);
}